// Round 1
// baseline (5060.646 us; speedup 1.0000x reference)
//
#include <hip/hip_runtime.h>
#include <hip/hip_bf16.h>
#include <hip/hip_fp16.h>

typedef _Float16 f16;
typedef _Float16 f16x8 __attribute__((ext_vector_type(8)));
typedef float f32x4 __attribute__((ext_vector_type(4)));

#define HB 2048
#define DD 2048
#define TT 256
#define BB 64

// ---------- phase 0: transpose + convert fp32 [R][C] -> fp16 [C][R] (square 2048) ----------
__global__ __launch_bounds__(256) void k_transpose_cvt(const float* __restrict__ src,
                                                       f16* __restrict__ dst) {
    __shared__ f16 tile[64][65];
    int bx = blockIdx.x * 64;  // col base in src
    int by = blockIdx.y * 64;  // row base in src
    int tx = threadIdx.x & 63;
    int ty = threadIdx.x >> 6;  // 0..3
#pragma unroll
    for (int r = ty; r < 64; r += 4)
        tile[r][tx] = (f16)src[(size_t)(by + r) * HB + bx + tx];
    __syncthreads();
#pragma unroll
    for (int r = ty; r < 64; r += 4)
        dst[(size_t)(bx + r) * HB + by + tx] = tile[tx][r];
}

// ---------- phase 1: xw[t*64+b][h] = sum_d x[b][t][d] * W[d][h] + bias[h] ----------
// A row r (= t*64+b) maps to x row (b*256 + t). W16T is [n][k] fp16.
// WG: 256 thr = 4 waves (2x2), wave tile 32x32 via 2x2 16x16x32 MFMA frags.
template <bool XF32>
__global__ __launch_bounds__(256) void k_gemm_xw(const float* __restrict__ x,
                                                 const f16* __restrict__ W16T,
                                                 const float* __restrict__ bias,
                                                 void* __restrict__ xw_out) {
    int lane = threadIdx.x & 63;
    int w = threadIdx.x >> 6;  // 0..3
    int wr = w >> 1, wc = w & 1;
    int rowBase = blockIdx.y * 64 + wr * 32;
    int colBase = blockIdx.x * 64 + wc * 32;
    int lr = lane & 15;
    int kg = lane >> 4;  // 0..3

    f32x4 acc[2][2] = {};

    int r0 = rowBase + lr;
    int r1 = rowBase + 16 + lr;
    const float* xrow0 = x + ((size_t)(r0 & 63) * TT + (r0 >> 6)) * DD;
    const float* xrow1 = x + ((size_t)(r1 & 63) * TT + (r1 >> 6)) * DD;
    const f16* wrow0 = W16T + (size_t)(colBase + lr) * DD;
    const f16* wrow1 = W16T + (size_t)(colBase + 16 + lr) * DD;

    for (int kk = 0; kk < DD; kk += 32) {
        int k = kk + kg * 8;
        const float4* pa0 = reinterpret_cast<const float4*>(xrow0 + k);
        const float4* pa1 = reinterpret_cast<const float4*>(xrow1 + k);
        float4 a0l = pa0[0], a0h = pa0[1];
        float4 a1l = pa1[0], a1h = pa1[1];
        f16x8 a0 = {(f16)a0l.x, (f16)a0l.y, (f16)a0l.z, (f16)a0l.w,
                    (f16)a0h.x, (f16)a0h.y, (f16)a0h.z, (f16)a0h.w};
        f16x8 a1 = {(f16)a1l.x, (f16)a1l.y, (f16)a1l.z, (f16)a1l.w,
                    (f16)a1h.x, (f16)a1h.y, (f16)a1h.z, (f16)a1h.w};
        f16x8 b0 = *reinterpret_cast<const f16x8*>(wrow0 + k);
        f16x8 b1 = *reinterpret_cast<const f16x8*>(wrow1 + k);
        acc[0][0] = __builtin_amdgcn_mfma_f32_16x16x32_f16(a0, b0, acc[0][0], 0, 0, 0);
        acc[0][1] = __builtin_amdgcn_mfma_f32_16x16x32_f16(a0, b1, acc[0][1], 0, 0, 0);
        acc[1][0] = __builtin_amdgcn_mfma_f32_16x16x32_f16(a1, b0, acc[1][0], 0, 0, 0);
        acc[1][1] = __builtin_amdgcn_mfma_f32_16x16x32_f16(a1, b1, acc[1][1], 0, 0, 0);
    }

#pragma unroll
    for (int mi = 0; mi < 2; ++mi)
#pragma unroll
        for (int ni = 0; ni < 2; ++ni) {
            int col = colBase + ni * 16 + lr;
            float bv = bias[col];
#pragma unroll
            for (int j = 0; j < 4; ++j) {
                int row = rowBase + mi * 16 + kg * 4 + j;
                float v = acc[mi][ni][j] + bv;
                if (XF32)
                    ((float*)xw_out)[(size_t)row * HB + col] = v;
                else
                    ((f16*)xw_out)[(size_t)row * HB + col] = (f16)v;
            }
        }
}

// ---------- phase 2: one recurrence step ----------
// grid (128, 2), block 128 (2 waves). Wave tile: 16 rows x 16 cols, K = 2048.
template <bool XF32>
__global__ __launch_bounds__(128) void k_rnn_step(const f16* __restrict__ hin,
                                                  const f16* __restrict__ WhT,
                                                  const void* __restrict__ xw_t,
                                                  f16* __restrict__ hout,
                                                  float* __restrict__ dout, int last) {
    int lane = threadIdx.x & 63;
    int w = threadIdx.x >> 6;  // 0..1
    int m0 = blockIdx.y * 32 + w * 16;
    int n0 = blockIdx.x * 16;
    int lr = lane & 15;
    int kg = lane >> 4;

    const f16* arow = hin + (size_t)(m0 + lr) * HB;
    const f16* brow = WhT + (size_t)(n0 + lr) * HB;

    f32x4 acc = {};
#pragma unroll 4
    for (int kk = 0; kk < HB; kk += 32) {
        int k = kk + kg * 8;
        f16x8 a = *reinterpret_cast<const f16x8*>(arow + k);
        f16x8 b = *reinterpret_cast<const f16x8*>(brow + k);
        acc = __builtin_amdgcn_mfma_f32_16x16x32_f16(a, b, acc, 0, 0, 0);
    }

#pragma unroll
    for (int j = 0; j < 4; ++j) {
        int row = m0 + kg * 4 + j;
        int col = n0 + lr;
        float xv = XF32 ? ((const float*)xw_t)[(size_t)row * HB + col]
                        : (float)((const f16*)xw_t)[(size_t)row * HB + col];
        float pre = acc[j] + xv;
        float h = tanhf(pre);
        hout[(size_t)row * HB + col] = (f16)h;
        if (last) dout[(size_t)row * HB + col] = h;
    }
}

extern "C" void kernel_launch(void* const* d_in, const int* in_sizes, int n_in,
                              void* d_out, int out_size, void* d_ws, size_t ws_size,
                              hipStream_t stream) {
    const float* x = (const float*)d_in[0];
    const float* W = (const float*)d_in[1];
    const float* Wh = (const float*)d_in[2];
    const float* bias = (const float*)d_in[3];
    float* dout = (float*)d_out;

    char* ws = (char*)d_ws;
    const size_t SZ_WT = (size_t)HB * DD * 2;       // 8 MB
    const size_t SZ_H = (size_t)BB * HB * 2;        // 256 KB
    f16* W16T = (f16*)(ws);
    f16* Wh16T = (f16*)(ws + SZ_WT);
    f16* h0 = (f16*)(ws + 2 * SZ_WT);
    f16* h1 = (f16*)(ws + 2 * SZ_WT + SZ_H);
    char* xw = ws + 2 * SZ_WT + 2 * SZ_H;

    const size_t need_f32 = 2 * SZ_WT + 2 * SZ_H + (size_t)TT * BB * HB * 4;
    bool xf32 = (ws_size >= need_f32);

    dim3 tgrid(32, 32);
    k_transpose_cvt<<<tgrid, 256, 0, stream>>>(W, W16T);
    k_transpose_cvt<<<tgrid, 256, 0, stream>>>(Wh, Wh16T);

    if (xf32)
        k_gemm_xw<true><<<dim3(32, 256), 256, 0, stream>>>(x, W16T, bias, xw);
    else
        k_gemm_xw<false><<<dim3(32, 256), 256, 0, stream>>>(x, W16T, bias, xw);

    hipMemsetAsync(h0, 0, SZ_H, stream);

    f16* hb[2] = {h0, h1};
    for (int t = 0; t < TT; ++t) {
        const void* xwt = xf32 ? (const void*)(xw + (size_t)t * BB * HB * 4)
                               : (const void*)(xw + (size_t)t * BB * HB * 2);
        f16* hin = hb[t & 1];
        f16* hout = hb[(t + 1) & 1];
        int last = (t == TT - 1);
        if (xf32)
            k_rnn_step<true><<<dim3(128, 2), 128, 0, stream>>>(hin, Wh16T, xwt, hout, dout, last);
        else
            k_rnn_step<false><<<dim3(128, 2), 128, 0, stream>>>(hin, Wh16T, xwt, hout, dout, last);
    }
}

// Round 2
// 3713.512 us; speedup vs baseline: 1.3628x; 1.3628x over previous
//
#include <hip/hip_runtime.h>
#include <hip/hip_bf16.h>
#include <hip/hip_fp16.h>

typedef _Float16 f16;
typedef _Float16 f16x8 __attribute__((ext_vector_type(8)));
typedef float f32x4 __attribute__((ext_vector_type(4)));
typedef unsigned int u32;

#define HB 2048
#define DD 2048
#define TT 256
#define BB 64
#define NWG 128

typedef const __attribute__((address_space(1))) u32 gu32;
typedef __attribute__((address_space(3))) u32 lu32;

__device__ __forceinline__ void gl_lds16(const void* g, void* l) {
    __builtin_amdgcn_global_load_lds((gu32*)g, (lu32*)l, 16, 0, 0);
}

// ---------- transpose + convert fp32 [R][C] -> fp16 [C][R] (square 2048) ----------
__global__ __launch_bounds__(256) void k_transpose_cvt(const float* __restrict__ src,
                                                       f16* __restrict__ dst) {
    __shared__ f16 tile[64][65];
    int bx = blockIdx.x * 64;
    int by = blockIdx.y * 64;
    int tx = threadIdx.x & 63;
    int ty = threadIdx.x >> 6;
#pragma unroll
    for (int r = ty; r < 64; r += 4)
        tile[r][tx] = (f16)src[(size_t)(by + r) * HB + bx + tx];
    __syncthreads();
#pragma unroll
    for (int r = ty; r < 64; r += 4)
        dst[(size_t)(bx + r) * HB + by + tx] = tile[tx][r];
}

// ---------- convert/gather x [b][t][d] fp32 -> a16 [t*64+b][d] fp16 ----------
__global__ __launch_bounds__(256) void k_cvt_x(const float* __restrict__ x,
                                               f16* __restrict__ a16) {
    int r = blockIdx.x;          // r = t*64+b
    int d = threadIdx.x * 8;
    const float* src = x + ((size_t)(r & 63) * TT + (r >> 6)) * DD + d;
    float4 v0 = *(const float4*)src;
    float4 v1 = *(const float4*)(src + 4);
    f16x8 o = {(f16)v0.x, (f16)v0.y, (f16)v0.z, (f16)v0.w,
               (f16)v1.x, (f16)v1.y, (f16)v1.z, (f16)v1.w};
    *(f16x8*)(a16 + (size_t)r * DD + d) = o;
}

// ---------- phase 1 (fast): 128x128x32 LDS-staged MFMA GEMM, xw16 = a16 @ W + b ----------
// A: a16 [16384][2048] f16 row-major. B: W16T [n][k] f16. Swizzle: phys_c2 = c2 ^ ((r>>1)&3).
__global__ __launch_bounds__(256) void k_gemm_xw_lds(const f16* __restrict__ a16,
                                                     const f16* __restrict__ W16T,
                                                     const float* __restrict__ bias,
                                                     f16* __restrict__ xw16) {
    __shared__ f16 As[128 * 32];
    __shared__ f16 Bs[128 * 32];
    int tid = threadIdx.x;
    int lane = tid & 63, w = tid >> 6;
    int wr = w >> 1, wc = w & 1;
    int lr = lane & 15, kg = lane >> 4;
    int rowBase = blockIdx.y * 128;
    int colBase = blockIdx.x * 128;

    f32x4 acc[4][4] = {};

    // staging: load L in {0,1}: unit u = L*256 + tid; r=u>>2; logical c2 = (u&3)^((r>>1)&3)
    int r0 = tid >> 2, c0 = ((tid & 3) ^ ((r0 >> 1) & 3)) * 8;
    int u1 = tid + 256;
    int r1 = u1 >> 2, c1 = ((u1 & 3) ^ ((r1 >> 1) & 3)) * 8;
    const f16* gA0 = a16 + (size_t)(rowBase + r0) * DD + c0;
    const f16* gA1 = a16 + (size_t)(rowBase + r1) * DD + c1;
    const f16* gB0 = W16T + (size_t)(colBase + r0) * DD + c0;
    const f16* gB1 = W16T + (size_t)(colBase + r1) * DD + c1;
    // wave-uniform LDS bases (HW adds lane*16)
    f16* lA0 = As + (size_t)(w * 64) * 8;
    f16* lA1 = As + (size_t)(256 + w * 64) * 8;
    f16* lB0 = Bs + (size_t)(w * 64) * 8;
    f16* lB1 = Bs + (size_t)(256 + w * 64) * 8;

    for (int kk = 0; kk < DD; kk += 32) {
        gl_lds16(gA0 + kk, lA0);
        gl_lds16(gA1 + kk, lA1);
        gl_lds16(gB0 + kk, lB0);
        gl_lds16(gB1 + kk, lB1);
        __syncthreads();

        f16x8 af[4], bf[4];
#pragma unroll
        for (int mi = 0; mi < 4; ++mi) {
            int row = wr * 64 + mi * 16 + lr;
            af[mi] = *(const f16x8*)(As + row * 32 + (kg ^ ((row >> 1) & 3)) * 8);
        }
#pragma unroll
        for (int ni = 0; ni < 4; ++ni) {
            int rowb = wc * 64 + ni * 16 + lr;
            bf[ni] = *(const f16x8*)(Bs + rowb * 32 + (kg ^ ((rowb >> 1) & 3)) * 8);
        }
#pragma unroll
        for (int mi = 0; mi < 4; ++mi)
#pragma unroll
            for (int ni = 0; ni < 4; ++ni)
                acc[mi][ni] = __builtin_amdgcn_mfma_f32_16x16x32_f16(af[mi], bf[ni],
                                                                     acc[mi][ni], 0, 0, 0);
        __syncthreads();
    }

#pragma unroll
    for (int mi = 0; mi < 4; ++mi)
#pragma unroll
        for (int ni = 0; ni < 4; ++ni) {
            int col = colBase + wc * 64 + ni * 16 + lr;
            float bv = bias[col];
#pragma unroll
            for (int j = 0; j < 4; ++j) {
                int row = rowBase + wr * 64 + mi * 16 + kg * 4 + j;
                xw16[(size_t)row * HB + col] = (f16)(acc[mi][ni][j] + bv);
            }
        }
}

// ---------- phase 1 (fallback, small ws): direct-load GEMM from fp32 x ----------
__global__ __launch_bounds__(256) void k_gemm_xw_direct(const float* __restrict__ x,
                                                        const f16* __restrict__ W16T,
                                                        const float* __restrict__ bias,
                                                        f16* __restrict__ xw16) {
    int lane = threadIdx.x & 63;
    int w = threadIdx.x >> 6;
    int wr = w >> 1, wc = w & 1;
    int rowBase = blockIdx.y * 64 + wr * 32;
    int colBase = blockIdx.x * 64 + wc * 32;
    int lr = lane & 15;
    int kg = lane >> 4;

    f32x4 acc[2][2] = {};

    int r0 = rowBase + lr;
    int r1 = rowBase + 16 + lr;
    const float* xrow0 = x + ((size_t)(r0 & 63) * TT + (r0 >> 6)) * DD;
    const float* xrow1 = x + ((size_t)(r1 & 63) * TT + (r1 >> 6)) * DD;
    const f16* wrow0 = W16T + (size_t)(colBase + lr) * DD;
    const f16* wrow1 = W16T + (size_t)(colBase + 16 + lr) * DD;

    for (int kk = 0; kk < DD; kk += 32) {
        int k = kk + kg * 8;
        const float4* pa0 = reinterpret_cast<const float4*>(xrow0 + k);
        const float4* pa1 = reinterpret_cast<const float4*>(xrow1 + k);
        float4 a0l = pa0[0], a0h = pa0[1];
        float4 a1l = pa1[0], a1h = pa1[1];
        f16x8 a0 = {(f16)a0l.x, (f16)a0l.y, (f16)a0l.z, (f16)a0l.w,
                    (f16)a0h.x, (f16)a0h.y, (f16)a0h.z, (f16)a0h.w};
        f16x8 a1 = {(f16)a1l.x, (f16)a1l.y, (f16)a1l.z, (f16)a1l.w,
                    (f16)a1h.x, (f16)a1h.y, (f16)a1h.z, (f16)a1h.w};
        f16x8 b0 = *reinterpret_cast<const f16x8*>(wrow0 + k);
        f16x8 b1 = *reinterpret_cast<const f16x8*>(wrow1 + k);
        acc[0][0] = __builtin_amdgcn_mfma_f32_16x16x32_f16(a0, b0, acc[0][0], 0, 0, 0);
        acc[0][1] = __builtin_amdgcn_mfma_f32_16x16x32_f16(a0, b1, acc[0][1], 0, 0, 0);
        acc[1][0] = __builtin_amdgcn_mfma_f32_16x16x32_f16(a1, b0, acc[1][0], 0, 0, 0);
        acc[1][1] = __builtin_amdgcn_mfma_f32_16x16x32_f16(a1, b1, acc[1][1], 0, 0, 0);
    }

#pragma unroll
    for (int mi = 0; mi < 2; ++mi)
#pragma unroll
        for (int ni = 0; ni < 2; ++ni) {
            int col = colBase + ni * 16 + lr;
            float bv = bias[col];
#pragma unroll
            for (int j = 0; j < 4; ++j) {
                int row = rowBase + mi * 16 + kg * 4 + j;
                xw16[(size_t)row * HB + col] = (f16)(acc[mi][ni][j] + bv);
            }
        }
}

// ---------- phase 2: persistent recurrence. 128 WGs x 512 thr (8 waves). ----------
// WG g owns cols [g*16, g*16+16); wave w owns K slice [w*256, (w+1)*256), Wh frags in regs.
__device__ __forceinline__ void gbar(u32* c, int t) {
    __syncthreads();
    if (threadIdx.x == 0) {
        __hip_atomic_fetch_add(c + t, 1u, __ATOMIC_RELEASE, __HIP_MEMORY_SCOPE_AGENT);
        while (__hip_atomic_load(c + t, __ATOMIC_ACQUIRE, __HIP_MEMORY_SCOPE_AGENT) < NWG)
            __builtin_amdgcn_s_sleep(2);
    }
    __syncthreads();
}

__global__ __launch_bounds__(512) void k_rnn_persist(const f16* __restrict__ Wh16T,
                                                     const f16* __restrict__ xw16,
                                                     f16* __restrict__ hA,
                                                     f16* __restrict__ hB,
                                                     float* __restrict__ dout,
                                                     u32* __restrict__ cnt) {
    __shared__ float red[8][4][16][16];  // [wave][m][col][row%16], 32KB
    int tid = threadIdx.x;
    int lane = tid & 63, w = tid >> 6;
    int lr = lane & 15, kg = lane >> 4;
    int n0 = blockIdx.x * 16;

    // preload B fragments: Wh16T[n0+lr][w*256 + s*32 + kg*8 .. +8]
    f16x8 bfrag[8];
    {
        const f16* brow = Wh16T + (size_t)(n0 + lr) * HB + w * 256 + kg * 8;
#pragma unroll
        for (int s = 0; s < 8; ++s) bfrag[s] = *(const f16x8*)(brow + s * 32);
    }

    f16* hbuf[2] = {hA, hB};
    int row0 = tid >> 4, colR = tid & 15;  // reduce assignment

    for (int t = 0; t < TT; ++t) {
        const f16* hin = hbuf[t & 1];
        f16* hout = hbuf[(t + 1) & 1];

        f32x4 acc[4] = {};
        if (t > 0) {
            const f16* abase = hin + w * 256 + kg * 8;
#pragma unroll
            for (int m = 0; m < 4; ++m) {
                const f16* ar = abase + (size_t)(m * 16 + lr) * HB;
#pragma unroll
                for (int s = 0; s < 8; ++s) {
                    f16x8 a = *(const f16x8*)(ar + s * 32);
                    acc[m] = __builtin_amdgcn_mfma_f32_16x16x32_f16(a, bfrag[s], acc[m], 0, 0, 0);
                }
            }
        }
        // write partials: red[w][m][col=lr][row%16 = kg*4+j]
#pragma unroll
        for (int m = 0; m < 4; ++m)
            *(f32x4*)&red[w][m][lr][kg * 4] = acc[m];
        __syncthreads();

        // reduce: thread -> outputs (row0, colR) and (row0+32, colR)
        float s0 = 0.f, s1 = 0.f;
        int m0 = row0 >> 4, rr = row0 & 15;
#pragma unroll
        for (int ww = 0; ww < 8; ++ww) {
            s0 += red[ww][m0][colR][rr];
            s1 += red[ww][m0 + 2][colR][rr];
        }
        size_t xo = ((size_t)t * BB + row0) * HB + n0 + colR;
        float p0 = s0 + (float)xw16[xo];
        float p1 = s1 + (float)xw16[xo + (size_t)32 * HB];
        float h0v = tanhf(p0), h1v = tanhf(p1);
        hout[(size_t)row0 * HB + n0 + colR] = (f16)h0v;
        hout[(size_t)(row0 + 32) * HB + n0 + colR] = (f16)h1v;
        if (t == TT - 1) {
            dout[(size_t)row0 * HB + n0 + colR] = h0v;
            dout[(size_t)(row0 + 32) * HB + n0 + colR] = h1v;
        } else {
            gbar(cnt, t);
        }
    }
}

extern "C" void kernel_launch(void* const* d_in, const int* in_sizes, int n_in,
                              void* d_out, int out_size, void* d_ws, size_t ws_size,
                              hipStream_t stream) {
    const float* x = (const float*)d_in[0];
    const float* W = (const float*)d_in[1];
    const float* Wh = (const float*)d_in[2];
    const float* bias = (const float*)d_in[3];
    float* dout = (float*)d_out;

    char* ws = (char*)d_ws;
    const size_t SZ_WT = (size_t)HB * DD * 2;   // 8 MB
    const size_t SZ_H = (size_t)BB * HB * 2;    // 256 KB
    const size_t SZ_XW = (size_t)TT * BB * HB * 2;  // 64 MB
    const size_t OFF_W = 0;
    const size_t OFF_WH = OFF_W + SZ_WT;
    const size_t OFF_H0 = OFF_WH + SZ_WT;
    const size_t OFF_H1 = OFF_H0 + SZ_H;
    const size_t OFF_CNT = OFF_H1 + SZ_H;
    const size_t OFF_XW = OFF_CNT + 4096;
    const size_t OFF_X16 = OFF_XW + SZ_XW;
    const size_t NEED_FULL = OFF_X16 + (size_t)TT * BB * DD * 2;

    f16* W16T = (f16*)(ws + OFF_W);
    f16* Wh16T = (f16*)(ws + OFF_WH);
    f16* h0 = (f16*)(ws + OFF_H0);
    f16* h1 = (f16*)(ws + OFF_H1);
    u32* cnt = (u32*)(ws + OFF_CNT);
    f16* xw16 = (f16*)(ws + OFF_XW);
    f16* x16 = (f16*)(ws + OFF_X16);

    dim3 tgrid(32, 32);
    k_transpose_cvt<<<tgrid, 256, 0, stream>>>(W, W16T);
    k_transpose_cvt<<<tgrid, 256, 0, stream>>>(Wh, Wh16T);

    if (ws_size >= NEED_FULL) {
        k_cvt_x<<<TT * BB, 256, 0, stream>>>(x, x16);
        k_gemm_xw_lds<<<dim3(HB / 128, TT * BB / 128), 256, 0, stream>>>(x16, W16T, bias, xw16);
    } else {
        k_gemm_xw_direct<<<dim3(HB / 64, TT * BB / 64), 256, 0, stream>>>(x, W16T, bias, xw16);
    }

    hipMemsetAsync(cnt, 0, TT * sizeof(u32), stream);
    k_rnn_persist<<<NWG, 512, 0, stream>>>(Wh16T, xw16, h0, h1, dout, cnt);
}